// Round 12
// baseline (178.011 us; speedup 1.0000x reference)
//
#include <hip/hip_runtime.h>
#include <stdint.h>
#include <math.h>

// Problem constants
#define NV   3000   // 3*N_VERT valid vertices
#define MP   3072   // padded M and K (multiple of 64/32)
#define NBC  2048   // B*C = 32*64
#define NMID 1000   // N_VERT

typedef unsigned short u16;
typedef short  s8vec __attribute__((ext_vector_type(8)));
typedef float  f4vec __attribute__((ext_vector_type(4)));

// Tiled operand layout ("fragment order"):
//   A: adjt[m64][kt 0..95][g 0..3][lane 0..63][8]   (64-row m-tiles, 32-k tiles)
//   B: xt  [nt][kt 0..95][g 0..7][lane 0..63][8]    (128-row n-tiles, 32-k tiles)
// element (row r, k c): g = r_local/16, lane = ((c&31)>>3)*16 + (r&15), j = c&7.
// One 1KB group = one gload16 (contiguous); LDS reads linear in lane.

__device__ __forceinline__ u16 f2b(float f) {
  union { float f; unsigned int u; } v; v.f = f;
  unsigned int r = v.u + 0x7FFFu + ((v.u >> 16) & 1u);
  return (u16)(r >> 16);
}
__device__ __forceinline__ float b2f(u16 u) {
  union { unsigned int u; float f; } v; v.u = ((unsigned int)u) << 16;
  return v.f;
}

// async global->LDS, 16B/lane; LDS dest = wave-uniform base + lane*16
__device__ __forceinline__ void gload16(const void* g, void* l) {
  __builtin_amdgcn_global_load_lds(
      (const __attribute__((address_space(1))) void*)g,
      (__attribute__((address_space(3))) void*)l, 16, 0, 0);
}

// ---------------------------------------------------------------------------
// Fused input conversion (one launch; r9 measured win).
//   blocks [0,2304):    adj (3000x3000 f32) -> adjt (tiled bf16, padded)
//   blocks [2304,3840): x (3000x2048 f32)  -> xt   (tiled bf16, padded)
//   blocks [3840,3936): W0/W1/W2 (64x128)  -> Wt   (B-frag tiled bf16)
__global__ void k_conv(const float* __restrict__ adj,
                       const float* __restrict__ x,
                       const float* __restrict__ W0,
                       const float* __restrict__ W1,
                       const float* __restrict__ W2,
                       u16* __restrict__ adjt,
                       u16* __restrict__ xt,
                       u16* __restrict__ Wt) {
  __shared__ __align__(16) u16 tb[64][80];
  const int bid = blockIdx.x;
  const int t   = threadIdx.x;

  if (bid < 2304) {                     // ---- adj -> adjt
    const int bx = bid % 48;            // k-tile of 64 cols
    const int by = bid / 48;            // m-tile of 64 rows
    { // read 64x64 f32 block, coalesced
      const int rl = t >> 2, quad = t & 3;
      const int r  = by * 64 + rl;
      const bool rok = (r < NV);
#pragma unroll
      for (int i = 0; i < 4; ++i) {
        int c = bx * 64 + quad * 16 + i * 4;
        float4 f = {0.f, 0.f, 0.f, 0.f};
        if (rok && c < NV) f = *(const float4*)(adj + (size_t)r * NV + c);
        ushort4 o;
        o.x = f2b(f.x); o.y = f2b(f.y); o.z = f2b(f.z); o.w = f2b(f.w);
        *(ushort4*)&tb[rl][quad * 16 + i * 4] = o;
      }
    }
    __syncthreads();
    { // write 2 contiguous 16B chunks per thread in tiled order
#pragma unroll
      for (int h = 0; h < 2; ++h) {
        int chunk = t * 2 + h;          // 0..511
        int sel  = chunk >> 8;          // kk half (2 per 64-col block)
        int g    = (chunk >> 6) & 3;
        int lane = chunk & 63;
        int row  = g * 16 + (lane & 15);
        int col  = sel * 32 + (lane >> 4) * 8;
        s8vec v = *(const s8vec*)&tb[row][col];
        size_t dst = ((size_t)(by * 96 + bx * 2 + sel) * 4 + g) * 512 + lane * 8;
        *(s8vec*)(adjt + dst) = v;
      }
    }
  } else if (bid < 3840) {              // ---- x -> xt
    const int r2 = bid - 2304;
    const int k0 = (r2 % 48) * 64;      // 48 k-tiles (vertices)
    const int n0 = (r2 / 48) * 64;      // 32 n-tiles (b*64 channels)
    int kl = t >> 4, ch = t & 15;
#pragma unroll
    for (int r = 0; r < 4; ++r) {
      int k = k0 + kl + r * 16;
      float4 f = {0.f, 0.f, 0.f, 0.f};
      if (k < NV) f = *(const float4*)(x + (size_t)k * NBC + n0 + ch * 4);
      tb[ch * 4 + 0][kl + r * 16] = f2b(f.x);
      tb[ch * 4 + 1][kl + r * 16] = f2b(f.y);
      tb[ch * 4 + 2][kl + r * 16] = f2b(f.z);
      tb[ch * 4 + 3][kl + r * 16] = f2b(f.w);
    }
    __syncthreads();
    int nl = t >> 4, kc = t & 15;
#pragma unroll
    for (int r = 0; r < 4; ++r) {
      int n = n0 + nl + r * 16;
      int k = k0 + kc * 4;
      ushort4 o;
      o.x = tb[nl + r * 16][kc * 4 + 0];
      o.y = tb[nl + r * 16][kc * 4 + 1];
      o.z = tb[nl + r * 16][kc * 4 + 2];
      o.w = tb[nl + r * 16][kc * 4 + 3];
      int nt = n >> 7, g = (n >> 4) & 7, lr = n & 15;
      int kk = k >> 5, hi = (k >> 3) & 3, j = k & 7;
      size_t dst = ((size_t)(nt * 96 + kk) * 8 + g) * 512 +
                   (size_t)(hi * 16 + lr) * 8 + j;
      *(ushort4*)(xt + dst) = o;
    }
  } else {                              // ---- W -> Wt
    int e = (bid - 3840) * 256 + t;     // 0..24575
    const float* W = (e < 8192) ? W0 : (e < 16384) ? W1 : W2;
    int r  = e & 8191;
    int kk = r >> 12, g = (r >> 9) & 7, ln = (r >> 3) & 63, jj = r & 7;
    int c = kk * 32 + (ln >> 4) * 8 + jj;
    int j = g * 16 + (ln & 15);
    Wt[e] = f2b(W[c * 128 + j]);
  }
}

// ---------------------------------------------------------------------------
// H-part (bf16) = adjt[128 rows] x xt^T over one K-slice (NKT kt-steps of 32).
// BM=128 BN=128 BK=32, 4 waves 2x2, wave-tile 64x64, BOTH operands via LDS.
// (r9 structure, measured best.)
// Time law (r7 evidence: partial@NKT=48 == full@NKT=48 duration despite
// 37.5% of the FLOPs): wall ~= NKT x ~1850 cyc per-block latency chain
// (vmcnt -> barrier -> ds_read -> MFMA serialized); co-residency raises
// utilization but doesn't shorten a block. Full gemm additionally sits at
// the LDS ceiling (~80 of 85 B/cyc at 3 blocks/CU) -> structurally done.
// Partial gemm is fixed by SHORTENING the chain: K-split-4 -> NKT=24.
// Staging: 16 x 1KB chunks/kt, exactly 4 per wave -> uniform vmcnt(4).
// 3 bufs x 16KB = 48KB -> 3 blocks/CU = 144KB LDS, 3 waves/SIMD.
// Pipeline: at kt s top, vmcnt(4) drains stage(s) (leaves stage(s+1)'s 4 in
// flight) -> barrier -> stage(s+2) issued AFTER the barrier overwrites the
// buffer last read at compute(s-1) -> race-free.
// Swizzle: nt fast (all 16 per XCD), mk slow -> per-XCD A slice L2-resident,
// B re-reads cluster temporally (r5 FETCH 52MB vs r4-backwards 117MB).
template <int NKT>
__global__ __launch_bounds__(256, 3) void k_gemm(
    const u16* __restrict__ At,    // adjt tiled
    const u16* __restrict__ Xt,    // x tiled
    u16* __restrict__ Cbase,       // K-slice outputs, slot stride cslot
    size_t cslot,                  // elements per C slot
    int mtbase,                    // first 128-row tile of the m-range
    int nmt,                       // # of 128-row m-tiles
    int crow0,                     // row offset subtracted on C store
    int chunk) {                   // gridDim.x / 8
  __shared__ __align__(16) u16 S[3 * 8192];  // 3 bufs x (A 8KB | B 8KB)

  const int bid = blockIdx.x;
  const int swz = (bid & 7) * chunk + (bid >> 3);   // XCD-chunked (grid%8==0)
  const int nt  = swz & 15;         // fast: all 16 nt within each XCD
  const int mk  = swz >> 4;         // slow: narrow mk range per XCD
  const int ks  = mk / nmt;         // K-slice
  const int mt  = mk - ks * nmt;
  const int kt0 = ks * NKT;

  const int tid  = threadIdx.x;
  const int w    = tid >> 6;
  const int lane = tid & 63;
  const int wr   = w >> 1;             // wave row (2): rows wr*64..+63
  const int wc   = w & 1;              // wave col (2): cols wc*64..+63

  // Staging: wave w stages chunks c = w*4 .. w*4+3.
  // c<8 -> A chunk: m64-half = c>>2, g = c&3 (kt stride 2048 elem).
  // c>=8 -> B chunk: group g = c-8 (kt stride 4096 elem).
  const int c0 = w * 4;
  const u16* src[4];
  int stp[4];
#pragma unroll
  for (int i = 0; i < 4; ++i) {
    int c = c0 + i;
    if (c < 8) {
      int m64 = (mtbase + mt) * 2 + (c >> 2);
      src[i] = At + ((size_t)(m64 * 96 + kt0) * 4 + (c & 3)) * 512 + lane * 8;
      stp[i] = 2048;
    } else {
      src[i] = Xt + ((size_t)(nt * 96 + kt0) * 8 + (c - 8)) * 512 + lane * 8;
      stp[i] = 4096;
    }
  }

  f4vec acc[4][4];
#pragma unroll
  for (int i = 0; i < 4; ++i)
#pragma unroll
    for (int j = 0; j < 4; ++j) acc[i][j] = (f4vec){0.f, 0.f, 0.f, 0.f};

  auto stage = [&](int buf, int s) {
    u16* d = S + buf * 8192 + c0 * 512;
#pragma unroll
    for (int i = 0; i < 4; ++i)
      gload16(src[i] + (size_t)s * stp[i], d + i * 512);
  };
  auto compute = [&](int buf) {
    const u16* Ab = S + buf * 8192 + (wr * 4) * 512 + lane * 8;
    const u16* Bb = S + buf * 8192 + 4096 + (wc * 4) * 512 + lane * 8;
    s8vec a[4], b[4];
#pragma unroll
    for (int mi = 0; mi < 4; ++mi)
      a[mi] = *(const s8vec*)(Ab + mi * 512);
#pragma unroll
    for (int ni = 0; ni < 4; ++ni)
      b[ni] = *(const s8vec*)(Bb + ni * 512);
    __builtin_amdgcn_s_setprio(1);
#pragma unroll
    for (int mi = 0; mi < 4; ++mi)
#pragma unroll
      for (int ni = 0; ni < 4; ++ni)
        acc[mi][ni] = __builtin_amdgcn_mfma_f32_16x16x32_bf16(
            a[mi], b[ni], acc[mi][ni], 0, 0, 0);
    __builtin_amdgcn_s_setprio(0);
  };

  // prologue: 8 loads in flight (stage 0, stage 1)
  stage(0, 0);
  stage(1, 1);

  // kt 0..NKT-4 (NKT-3 divisible by 3; buf period 3)
#pragma unroll 1
  for (int sb = 0; sb < NKT - 3; sb += 3) {
#pragma unroll
    for (int u = 0; u < 3; ++u) {
      const int s = sb + u;
      asm volatile("s_waitcnt vmcnt(4)" ::: "memory");  // stage(s) landed
      asm volatile("s_barrier" ::: "memory");
      stage((u + 2) % 3, s + 2);
      compute(u);
    }
  }
  // kt NKT-3
  asm volatile("s_waitcnt vmcnt(4)" ::: "memory");
  asm volatile("s_barrier" ::: "memory");
  stage(2, NKT - 1);
  compute(0);
  // kt NKT-2
  asm volatile("s_waitcnt vmcnt(4)" ::: "memory");
  asm volatile("s_barrier" ::: "memory");
  compute(1);
  // kt NKT-1
  asm volatile("s_waitcnt vmcnt(0)" ::: "memory");
  asm volatile("s_barrier" ::: "memory");
  compute(2);

  // D layout: col = lane&15, row = (lane>>4)*4 + reg.  bf16 store.
  u16* Cs = Cbase + (size_t)ks * cslot;
  const int rl = lane & 15;
  const int rh = lane >> 4;
  const int mrow0 = (mtbase + mt) * 128 + wr * 64 - crow0;
#pragma unroll
  for (int mi = 0; mi < 4; ++mi)
#pragma unroll
    for (int ni = 0; ni < 4; ++ni) {
      int grow = mrow0 + mi * 16 + rh * 4;
      int gcol = nt * 128 + wc * 64 + ni * 16 + rl;
      u16* cp = Cs + (size_t)grow * NBC + gcol;
      cp[0 * NBC] = f2b(acc[mi][ni][0]);
      cp[1 * NBC] = f2b(acc[mi][ni][1]);
      cp[2 * NBC] = f2b(acc[mi][ni][2]);
      cp[3 * NBC] = f2b(acc[mi][ni][3]);
    }
}

// ---------------------------------------------------------------------------
// MFMA layerB, LDS-staged (r9 exact, layers 0/1): block = 128 vertices x 1
// batch. H comes as TWO bf16 K-slice partials; summed inside the f32 MFMA
// accumulator (K-doubling: 4 kk-slices of 32) -> no extra rounding of the
// sum. lr[v][j] = (H0+H1)[v][:] @ W[:][j] + bias; GLU; out store/max; tiled
// x_next write. j-pairing keeps GLU's (j, j+64) pair in-register.
template <int LAYER0, int WRITEX>
__global__ __launch_bounds__(256) void k_layerB(
    const u16* __restrict__ H0,     // bf16 [*][2048] K-slice 0
    const u16* __restrict__ H1,     // K-slice 1
    const u16* __restrict__ Wt,     // tiled [2][8][64][8] bf16
    const float* __restrict__ bias, // 128 f32
    u16* __restrict__ xt,           // tiled x_next
    float* __restrict__ out,
    int vt0) {
  __shared__ __align__(16) u16 Hs[2][2][8][64][8];   // 32KB, A-frag order

  const int vt = vt0 + blockIdx.x;
  const int b  = blockIdx.y;
  const int v0 = vt * 128;
  const int t  = threadIdx.x;

  // stage both H-slice tiles (128 v x 64 c each) into fragment-order LDS
#pragma unroll
  for (int h = 0; h < 2; ++h) {
    const u16* H = h ? H1 : H0;
#pragma unroll
    for (int q = 0; q < 4; ++q) {
      int id = q * 256 + t;          // 0..1023
      int v  = id >> 3;              // 0..127
      int cc = (id & 7) * 8;         // 0,8,..,56
      s8vec hh = *(const s8vec*)(H + (size_t)(v0 + v) * NBC + b * 64 + cc);
      int kk = cc >> 5, g = v >> 4, ln = ((cc >> 3) & 3) * 16 + (v & 15);
      *(s8vec*)&Hs[h][kk][g][ln][0] = hh;
    }
  }
  __syncthreads();

  const int w    = t >> 6;
  const int lane = t & 63;
  const int wvh  = w >> 1;         // v-half (2)
  const int wc   = w & 1;          // j-quarter pairing (2)

  s8vec bf[4][2];
#pragma unroll
  for (int ni = 0; ni < 4; ++ni) {
    int g = (ni < 2) ? (wc * 2 + ni) : (4 + wc * 2 + (ni - 2));
#pragma unroll
    for (int kk = 0; kk < 2; ++kk)
      bf[ni][kk] = *(const s8vec*)(Wt + ((size_t)(kk * 8 + g) * 64 + lane) * 8);
  }

  f4vec acc[4][4];
#pragma unroll
  for (int i = 0; i < 4; ++i)
#pragma unroll
    for (int j = 0; j < 4; ++j) acc[i][j] = (f4vec){0.f, 0.f, 0.f, 0.f};

#pragma unroll
  for (int h = 0; h < 2; ++h)
#pragma unroll
    for (int kk = 0; kk < 2; ++kk) {
      s8vec a[4];
#pragma unroll
      for (int mi = 0; mi < 4; ++mi)
        a[mi] = *(const s8vec*)&Hs[h][kk][wvh * 4 + mi][lane][0];
#pragma unroll
      for (int mi = 0; mi < 4; ++mi)
#pragma unroll
        for (int ni = 0; ni < 4; ++ni)
          acc[mi][ni] = __builtin_amdgcn_mfma_f32_16x16x32_bf16(
              a[mi], bf[ni][kk], acc[mi][ni], 0, 0, 0);
    }

  // epilogue: D col = lane&15 (j within 16), row = (lane>>4)*4 + reg (v)
  const int lr = lane & 15;
  const int rh = lane >> 4;
#pragma unroll
  for (int mi = 0; mi < 4; ++mi) {
    const int vbase = v0 + wvh * 64 + mi * 16 + rh * 4;
#pragma unroll
    for (int np = 0; np < 2; ++np) {
      const int j  = wc * 32 + np * 16 + lr;
      const float bl = bias[j];
      const float bh = bias[j + 64];
      float vals[4];
#pragma unroll
      for (int r = 0; r < 4; ++r) {
        float lo = acc[mi][np][r] + bl;
        float hi = acc[mi][np + 2][r] + bh;
        float gv = lo / (1.0f + __expf(-hi));
        vals[r] = ((vbase + r) < NV) ? gv : 0.0f;
      }
#pragma unroll
      for (int r = 0; r < 4; ++r) {
        int vg = vbase + r;
        if (vg >= NMID && vg < 2 * NMID) {
          size_t oi = (size_t)(vg - NMID) * NBC + b * 64 + j;
          if (LAYER0) out[oi] = vals[r];
          else        out[oi] = fmaxf(out[oi], vals[r]);
        }
      }
      if (WRITEX) {   // tiled write: k = vbase..+3, n = b*64 + j
        int n   = b * 64 + j;
        int nt  = n >> 7, g2 = (n >> 4) & 7, ln2 = n & 15;
        int kk2 = vbase >> 5, hi2 = (vbase >> 3) & 3, jj0 = vbase & 7;
        ushort4 o;
        o.x = f2b(vals[0]); o.y = f2b(vals[1]);
        o.z = f2b(vals[2]); o.w = f2b(vals[3]);
        size_t dst = ((size_t)(nt * 96 + kk2) * 8 + g2) * 512 +
                     (size_t)(hi2 * 16 + ln2) * 8 + jj0;
        *(ushort4*)(xt + dst) = o;
      }
    }
  }
}

// ---------------------------------------------------------------------------
// Final layerB, no-LDS (layer 2, NH=4 K-slices): A-fragments read straight
// from global H (r11-validated pattern; no 64KB LDS stage, no barrier):
// frag element j for lane l is
//   H[v0 + (wvh*4+mi)*16 + (l&15)][b*64 + kk*32 + (l>>4)*8 + j]
// = one contiguous s8vec load. H is L2/L3-warm from the gemm. The 4 slices
// are summed inside the f32 MFMA accumulator (8 kk-slices of 32).
__global__ __launch_bounds__(256) void k_layerB4(
    const u16* __restrict__ H0, const u16* __restrict__ H1,
    const u16* __restrict__ H2, const u16* __restrict__ H3,
    const u16* __restrict__ Wt,     // tiled [2][8][64][8] bf16
    const float* __restrict__ bias, // 128 f32
    float* __restrict__ out,
    int vt0) {
  const u16* Hp[4] = {H0, H1, H2, H3};
  const int vt = vt0 + blockIdx.x;
  const int b  = blockIdx.y;
  const int v0 = vt * 128;
  const int t  = threadIdx.x;

  const int w    = t >> 6;
  const int lane = t & 63;
  const int wvh  = w >> 1;         // v-half (2)
  const int wc   = w & 1;          // j-quarter pairing (2)

  s8vec bf[4][2];
#pragma unroll
  for (int ni = 0; ni < 4; ++ni) {
    int g = (ni < 2) ? (wc * 2 + ni) : (4 + wc * 2 + (ni - 2));
#pragma unroll
    for (int kk = 0; kk < 2; ++kk)
      bf[ni][kk] = *(const s8vec*)(Wt + ((size_t)(kk * 8 + g) * 64 + lane) * 8);
  }

  f4vec acc[4][4];
#pragma unroll
  for (int i = 0; i < 4; ++i)
#pragma unroll
    for (int j = 0; j < 4; ++j) acc[i][j] = (f4vec){0.f, 0.f, 0.f, 0.f};

  const size_t fbase =
      (size_t)(v0 + wvh * 64 + (lane & 15)) * NBC + b * 64 + (lane >> 4) * 8;
#pragma unroll
  for (int h = 0; h < 4; ++h) {
    const u16* hp = Hp[h] + fbase;
#pragma unroll
    for (int kk = 0; kk < 2; ++kk) {
      s8vec a[4];
#pragma unroll
      for (int mi = 0; mi < 4; ++mi)
        a[mi] = *(const s8vec*)(hp + (size_t)(mi * 16) * NBC + kk * 32);
#pragma unroll
      for (int mi = 0; mi < 4; ++mi)
#pragma unroll
        for (int ni = 0; ni < 4; ++ni)
          acc[mi][ni] = __builtin_amdgcn_mfma_f32_16x16x32_bf16(
              a[mi], bf[ni][kk], acc[mi][ni], 0, 0, 0);
    }
  }

  // epilogue: D col = lane&15 (j within 16), row = (lane>>4)*4 + reg (v)
  const int lr = lane & 15;
  const int rh = lane >> 4;
#pragma unroll
  for (int mi = 0; mi < 4; ++mi) {
    const int vbase = v0 + wvh * 64 + mi * 16 + rh * 4;
#pragma unroll
    for (int np = 0; np < 2; ++np) {
      const int j  = wc * 32 + np * 16 + lr;
      const float bl = bias[j];
      const float bh = bias[j + 64];
#pragma unroll
      for (int r = 0; r < 4; ++r) {
        float lo = acc[mi][np][r] + bl;
        float hi = acc[mi][np + 2][r] + bh;
        float gv = lo / (1.0f + __expf(-hi));
        int vg = vbase + r;
        if (vg >= NMID && vg < 2 * NMID) {
          size_t oi = (size_t)(vg - NMID) * NBC + b * 64 + j;
          out[oi] = fmaxf(out[oi], (vg < NV) ? gv : 0.0f);
        }
      }
    }
  }
}

// ---------------------------------------------------------------------------
// Buffer rotation: xa always holds the current tiled x (layerB writes x_next
// back into xa after the gemm has fully consumed it); Hbuf (25.2 MB) holds
// the K-slice partials: 2 full-size slots (layers 0/1, split-2) or 4
// 9-tile slots (layer 2, split-4: 4 x 4.7 MB = 18.9 MB, fits).
extern "C" void kernel_launch(void* const* d_in, const int* in_sizes, int n_in,
                              void* d_out, int out_size, void* d_ws, size_t ws_size,
                              hipStream_t stream) {
  const float* x   = (const float*)d_in[0];
  const float* adj = (const float*)d_in[1];
  const float* W0  = (const float*)d_in[2];
  const float* b0  = (const float*)d_in[3];
  const float* W1  = (const float*)d_in[4];
  const float* b1  = (const float*)d_in[5];
  const float* W2  = (const float*)d_in[6];
  const float* b2  = (const float*)d_in[7];
  float* out = (float*)d_out;

  char* ws = (char*)d_ws;
  u16* adjt = (u16*)ws;                                  // 18,874,368 B
  u16* xa   = (u16*)(ws + 18874368);                     // 12,582,912 B
  u16* Hbuf = (u16*)(ws + 18874368 + 12582912);          // 25,165,824 B
  u16* Wt   = (u16*)(ws + 18874368 + 12582912 + 25165824); //   49,152 B
  // total ws use: ~56.7 MB

  const size_t FS = (size_t)3072 * NBC;   // full-M slot (layers 0/1, split-2)
  const size_t PS = (size_t)1152 * NBC;   // 9-tile slot (layer 2, split-4)
  const size_t R0 = (size_t)896 * NBC;    // layer-2 row-compaction offset

  // fused input conversion: adj (2304 blocks) | x (1536) | W (96)
  k_conv<<<3936, 256, 0, stream>>>(adj, x, W0, W1, W2, adjt, xa, Wt);

  // layer 0: full M, K split 2 -> 24*16*2 = 768 blocks = 3/CU, NKT=48
  k_gemm<48><<<768, 256, 0, stream>>>(adjt, xa, Hbuf, FS, 0, 24, 0, 96);
  k_layerB<1, 1><<<dim3(24, 32), 256, 0, stream>>>(
      Hbuf, Hbuf + FS, Wt, b0, xa, out, 0);
  // layer 1: full M
  k_gemm<48><<<768, 256, 0, stream>>>(adjt, xa, Hbuf, FS, 0, 24, 0, 96);
  k_layerB<0, 1><<<dim3(24, 32), 256, 0, stream>>>(
      Hbuf, Hbuf + FS, Wt + 8192, b1, xa, out, 0);
  // layer 2: rows [896,2048) (EXACTLY 9 m-tiles), K split 4 -> NKT=24,
  // 9*16*4 = 576 blocks (all co-resident; per-block chain halved: ~37->~19us)
  k_gemm<24><<<576, 256, 0, stream>>>(adjt, xa, Hbuf, PS, 7, 9, 896, 72);
  k_layerB4<<<dim3(9, 32), 256, 0, stream>>>(
      Hbuf - R0, Hbuf + PS - R0, Hbuf + 2 * PS - R0, Hbuf + 3 * PS - R0,
      Wt + 16384, b2, out, 7);
}

// Round 13
// 172.317 us; speedup vs baseline: 1.0330x; 1.0330x over previous
//
#include <hip/hip_runtime.h>
#include <stdint.h>
#include <math.h>

// Problem constants
#define NV   3000   // 3*N_VERT valid vertices
#define MP   3072   // padded M and K (multiple of 64/32)
#define NBC  2048   // B*C = 32*64
#define NMID 1000   // N_VERT

typedef unsigned short u16;
typedef short  s8vec __attribute__((ext_vector_type(8)));
typedef float  f4vec __attribute__((ext_vector_type(4)));

// Tiled operand layout ("fragment order"):
//   A: adjt[m64][kt 0..95][g 0..3][lane 0..63][8]   (64-row m-tiles, 32-k tiles)
//   B: xt  [nt][kt 0..95][g 0..7][lane 0..63][8]    (128-row n-tiles, 32-k tiles)
// element (row r, k c): g = r_local/16, lane = ((c&31)>>3)*16 + (r&15), j = c&7.
// One 1KB group = one gload16 (contiguous); LDS reads linear in lane.

__device__ __forceinline__ u16 f2b(float f) {
  union { float f; unsigned int u; } v; v.f = f;
  unsigned int r = v.u + 0x7FFFu + ((v.u >> 16) & 1u);
  return (u16)(r >> 16);
}
__device__ __forceinline__ float b2f(u16 u) {
  union { unsigned int u; float f; } v; v.u = ((unsigned int)u) << 16;
  return v.f;
}

// async global->LDS, 16B/lane; LDS dest = wave-uniform base + lane*16
__device__ __forceinline__ void gload16(const void* g, void* l) {
  __builtin_amdgcn_global_load_lds(
      (const __attribute__((address_space(1))) void*)g,
      (__attribute__((address_space(3))) void*)l, 16, 0, 0);
}

// ---------------------------------------------------------------------------
// Fused input conversion (one launch; r9 measured win).
//   blocks [0,2304):    adj (3000x3000 f32) -> adjt (tiled bf16, padded)
//   blocks [2304,3840): x (3000x2048 f32)  -> xt   (tiled bf16, padded)
//   blocks [3840,3936): W0/W1/W2 (64x128)  -> Wt   (B-frag tiled bf16)
__global__ void k_conv(const float* __restrict__ adj,
                       const float* __restrict__ x,
                       const float* __restrict__ W0,
                       const float* __restrict__ W1,
                       const float* __restrict__ W2,
                       u16* __restrict__ adjt,
                       u16* __restrict__ xt,
                       u16* __restrict__ Wt) {
  __shared__ __align__(16) u16 tb[64][80];
  const int bid = blockIdx.x;
  const int t   = threadIdx.x;

  if (bid < 2304) {                     // ---- adj -> adjt
    const int bx = bid % 48;            // k-tile of 64 cols
    const int by = bid / 48;            // m-tile of 64 rows
    { // read 64x64 f32 block, coalesced
      const int rl = t >> 2, quad = t & 3;
      const int r  = by * 64 + rl;
      const bool rok = (r < NV);
#pragma unroll
      for (int i = 0; i < 4; ++i) {
        int c = bx * 64 + quad * 16 + i * 4;
        float4 f = {0.f, 0.f, 0.f, 0.f};
        if (rok && c < NV) f = *(const float4*)(adj + (size_t)r * NV + c);
        ushort4 o;
        o.x = f2b(f.x); o.y = f2b(f.y); o.z = f2b(f.z); o.w = f2b(f.w);
        *(ushort4*)&tb[rl][quad * 16 + i * 4] = o;
      }
    }
    __syncthreads();
    { // write 2 contiguous 16B chunks per thread in tiled order
#pragma unroll
      for (int h = 0; h < 2; ++h) {
        int chunk = t * 2 + h;          // 0..511
        int sel  = chunk >> 8;          // kk half (2 per 64-col block)
        int g    = (chunk >> 6) & 3;
        int lane = chunk & 63;
        int row  = g * 16 + (lane & 15);
        int col  = sel * 32 + (lane >> 4) * 8;
        s8vec v = *(const s8vec*)&tb[row][col];
        size_t dst = ((size_t)(by * 96 + bx * 2 + sel) * 4 + g) * 512 + lane * 8;
        *(s8vec*)(adjt + dst) = v;
      }
    }
  } else if (bid < 3840) {              // ---- x -> xt
    const int r2 = bid - 2304;
    const int k0 = (r2 % 48) * 64;      // 48 k-tiles (vertices)
    const int n0 = (r2 / 48) * 64;      // 32 n-tiles (b*64 channels)
    int kl = t >> 4, ch = t & 15;
#pragma unroll
    for (int r = 0; r < 4; ++r) {
      int k = k0 + kl + r * 16;
      float4 f = {0.f, 0.f, 0.f, 0.f};
      if (k < NV) f = *(const float4*)(x + (size_t)k * NBC + n0 + ch * 4);
      tb[ch * 4 + 0][kl + r * 16] = f2b(f.x);
      tb[ch * 4 + 1][kl + r * 16] = f2b(f.y);
      tb[ch * 4 + 2][kl + r * 16] = f2b(f.z);
      tb[ch * 4 + 3][kl + r * 16] = f2b(f.w);
    }
    __syncthreads();
    int nl = t >> 4, kc = t & 15;
#pragma unroll
    for (int r = 0; r < 4; ++r) {
      int n = n0 + nl + r * 16;
      int k = k0 + kc * 4;
      ushort4 o;
      o.x = tb[nl + r * 16][kc * 4 + 0];
      o.y = tb[nl + r * 16][kc * 4 + 1];
      o.z = tb[nl + r * 16][kc * 4 + 2];
      o.w = tb[nl + r * 16][kc * 4 + 3];
      int nt = n >> 7, g = (n >> 4) & 7, lr = n & 15;
      int kk = k >> 5, hi = (k >> 3) & 3, j = k & 7;
      size_t dst = ((size_t)(nt * 96 + kk) * 8 + g) * 512 +
                   (size_t)(hi * 16 + lr) * 8 + j;
      *(ushort4*)(xt + dst) = o;
    }
  } else {                              // ---- W -> Wt
    int e = (bid - 3840) * 256 + t;     // 0..24575
    const float* W = (e < 8192) ? W0 : (e < 16384) ? W1 : W2;
    int r  = e & 8191;
    int kk = r >> 12, g = (r >> 9) & 7, ln = (r >> 3) & 63, jj = r & 7;
    int c = kk * 32 + (ln >> 4) * 8 + jj;
    int j = g * 16 + (ln & 15);
    Wt[e] = f2b(W[c * 128 + j]);
  }
}

// ---------------------------------------------------------------------------
// H-part (bf16) = adjt[128 rows] x xt^T over one K-slice (NKT kt-steps of 32).
// BM=128 BN=128 BK=32, 4 waves 2x2, wave-tile 64x64, BOTH operands via LDS.
// (r9 structure, session-best measured: total 172.9us.)
// The wall is the three-way balance per CU-kt at 3 blocks/CU: MFMA ~931 cyc,
// LDS-RW 144KB (~1700 cyc at the ~85 B/cyc ds ceiling), VMEM 48KB. All
// explored alternatives (tile 64/96/192, B-in-regs, no-LDS, K-split 3/4,
// BK=64, 8 structural rounds) regressed against this configuration.
// Staging: 16 x 1KB chunks/kt, exactly 4 per wave -> uniform vmcnt(4).
// 3 bufs x 16KB = 48KB -> 3 blocks/CU = 144KB LDS, 3 waves/SIMD.
// Pipeline: at kt s top, vmcnt(4) drains stage(s) (leaves stage(s+1)'s 4 in
// flight) -> barrier -> stage(s+2) issued AFTER the barrier overwrites the
// buffer last read at compute(s-1) -> race-free.
// Swizzle: nt fast (all 16 per XCD), mk slow -> per-XCD A slice L2-resident,
// B re-reads cluster temporally (r5 FETCH 52MB vs r4-backwards 117MB).
template <int NKT>
__global__ __launch_bounds__(256, 3) void k_gemm(
    const u16* __restrict__ At,    // adjt tiled
    const u16* __restrict__ Xt,    // x tiled
    u16* __restrict__ Cbase,       // K-slice outputs, slot stride cslot
    size_t cslot,                  // elements per C slot
    int mtbase,                    // first 128-row tile of the m-range
    int nmt,                       // # of 128-row m-tiles
    int crow0,                     // row offset subtracted on C store
    int chunk) {                   // gridDim.x / 8
  __shared__ __align__(16) u16 S[3 * 8192];  // 3 bufs x (A 8KB | B 8KB)

  const int bid = blockIdx.x;
  const int swz = (bid & 7) * chunk + (bid >> 3);   // XCD-chunked (grid%8==0)
  const int nt  = swz & 15;         // fast: all 16 nt within each XCD
  const int mk  = swz >> 4;         // slow: narrow mk range per XCD
  const int ks  = mk / nmt;         // K-slice
  const int mt  = mk - ks * nmt;
  const int kt0 = ks * NKT;

  const int tid  = threadIdx.x;
  const int w    = tid >> 6;
  const int lane = tid & 63;
  const int wr   = w >> 1;             // wave row (2): rows wr*64..+63
  const int wc   = w & 1;              // wave col (2): cols wc*64..+63

  // Staging: wave w stages chunks c = w*4 .. w*4+3.
  // c<8 -> A chunk: m64-half = c>>2, g = c&3 (kt stride 2048 elem).
  // c>=8 -> B chunk: group g = c-8 (kt stride 4096 elem).
  const int c0 = w * 4;
  const u16* src[4];
  int stp[4];
#pragma unroll
  for (int i = 0; i < 4; ++i) {
    int c = c0 + i;
    if (c < 8) {
      int m64 = (mtbase + mt) * 2 + (c >> 2);
      src[i] = At + ((size_t)(m64 * 96 + kt0) * 4 + (c & 3)) * 512 + lane * 8;
      stp[i] = 2048;
    } else {
      src[i] = Xt + ((size_t)(nt * 96 + kt0) * 8 + (c - 8)) * 512 + lane * 8;
      stp[i] = 4096;
    }
  }

  f4vec acc[4][4];
#pragma unroll
  for (int i = 0; i < 4; ++i)
#pragma unroll
    for (int j = 0; j < 4; ++j) acc[i][j] = (f4vec){0.f, 0.f, 0.f, 0.f};

  auto stage = [&](int buf, int s) {
    u16* d = S + buf * 8192 + c0 * 512;
#pragma unroll
    for (int i = 0; i < 4; ++i)
      gload16(src[i] + (size_t)s * stp[i], d + i * 512);
  };
  auto compute = [&](int buf) {
    const u16* Ab = S + buf * 8192 + (wr * 4) * 512 + lane * 8;
    const u16* Bb = S + buf * 8192 + 4096 + (wc * 4) * 512 + lane * 8;
    s8vec a[4], b[4];
#pragma unroll
    for (int mi = 0; mi < 4; ++mi)
      a[mi] = *(const s8vec*)(Ab + mi * 512);
#pragma unroll
    for (int ni = 0; ni < 4; ++ni)
      b[ni] = *(const s8vec*)(Bb + ni * 512);
    __builtin_amdgcn_s_setprio(1);
#pragma unroll
    for (int mi = 0; mi < 4; ++mi)
#pragma unroll
      for (int ni = 0; ni < 4; ++ni)
        acc[mi][ni] = __builtin_amdgcn_mfma_f32_16x16x32_bf16(
            a[mi], b[ni], acc[mi][ni], 0, 0, 0);
    __builtin_amdgcn_s_setprio(0);
  };

  // prologue: 8 loads in flight (stage 0, stage 1)
  stage(0, 0);
  stage(1, 1);

  // kt 0..NKT-4 (NKT-3 divisible by 3; buf period 3)
#pragma unroll 1
  for (int sb = 0; sb < NKT - 3; sb += 3) {
#pragma unroll
    for (int u = 0; u < 3; ++u) {
      const int s = sb + u;
      asm volatile("s_waitcnt vmcnt(4)" ::: "memory");  // stage(s) landed
      asm volatile("s_barrier" ::: "memory");
      stage((u + 2) % 3, s + 2);
      compute(u);
    }
  }
  // kt NKT-3
  asm volatile("s_waitcnt vmcnt(4)" ::: "memory");
  asm volatile("s_barrier" ::: "memory");
  stage(2, NKT - 1);
  compute(0);
  // kt NKT-2
  asm volatile("s_waitcnt vmcnt(4)" ::: "memory");
  asm volatile("s_barrier" ::: "memory");
  compute(1);
  // kt NKT-1
  asm volatile("s_waitcnt vmcnt(0)" ::: "memory");
  asm volatile("s_barrier" ::: "memory");
  compute(2);

  // D layout: col = lane&15, row = (lane>>4)*4 + reg.  bf16 store.
  u16* Cs = Cbase + (size_t)ks * cslot;
  const int rl = lane & 15;
  const int rh = lane >> 4;
  const int mrow0 = (mtbase + mt) * 128 + wr * 64 - crow0;
#pragma unroll
  for (int mi = 0; mi < 4; ++mi)
#pragma unroll
    for (int ni = 0; ni < 4; ++ni) {
      int grow = mrow0 + mi * 16 + rh * 4;
      int gcol = nt * 128 + wc * 64 + ni * 16 + rl;
      u16* cp = Cs + (size_t)grow * NBC + gcol;
      cp[0 * NBC] = f2b(acc[mi][ni][0]);
      cp[1 * NBC] = f2b(acc[mi][ni][1]);
      cp[2 * NBC] = f2b(acc[mi][ni][2]);
      cp[3 * NBC] = f2b(acc[mi][ni][3]);
    }
}

// ---------------------------------------------------------------------------
// MFMA layerB: block = 128 vertices x 1 batch (64 ch -> 128 j).
// H comes as TWO bf16 K-slice partials; summed inside the f32 MFMA
// accumulator (K-doubling: 4 kk-slices of 32) -> no extra rounding of the
// sum. lr[v][j] = (H0+H1)[v][:] @ W[:][j] + bias; GLU; out store/max; tiled
// x_next write. j-pairing keeps GLU's (j, j+64) pair in-register.
// LDS-staged (r9 exact): direct-global A-frag variants (r11/r12) regressed
// from sibling-wave read duplication.
template <int LAYER0, int WRITEX>
__global__ __launch_bounds__(256) void k_layerB(
    const u16* __restrict__ H0,     // bf16 [*][2048] K-slice 0
    const u16* __restrict__ H1,     // K-slice 1
    const u16* __restrict__ Wt,     // tiled [2][8][64][8] bf16
    const float* __restrict__ bias, // 128 f32
    u16* __restrict__ xt,           // tiled x_next
    float* __restrict__ out,
    int vt0) {
  __shared__ __align__(16) u16 Hs[2][2][8][64][8];   // 32KB, A-frag order

  const int vt = vt0 + blockIdx.x;
  const int b  = blockIdx.y;
  const int v0 = vt * 128;
  const int t  = threadIdx.x;

  // stage both H-slice tiles (128 v x 64 c each) into fragment-order LDS
#pragma unroll
  for (int h = 0; h < 2; ++h) {
    const u16* H = h ? H1 : H0;
#pragma unroll
    for (int q = 0; q < 4; ++q) {
      int id = q * 256 + t;          // 0..1023
      int v  = id >> 3;              // 0..127
      int cc = (id & 7) * 8;         // 0,8,..,56
      s8vec hh = *(const s8vec*)(H + (size_t)(v0 + v) * NBC + b * 64 + cc);
      int kk = cc >> 5, g = v >> 4, ln = ((cc >> 3) & 3) * 16 + (v & 15);
      *(s8vec*)&Hs[h][kk][g][ln][0] = hh;
    }
  }
  __syncthreads();

  const int w    = t >> 6;
  const int lane = t & 63;
  const int wvh  = w >> 1;         // v-half (2)
  const int wc   = w & 1;          // j-quarter pairing (2)

  s8vec bf[4][2];
#pragma unroll
  for (int ni = 0; ni < 4; ++ni) {
    int g = (ni < 2) ? (wc * 2 + ni) : (4 + wc * 2 + (ni - 2));
#pragma unroll
    for (int kk = 0; kk < 2; ++kk)
      bf[ni][kk] = *(const s8vec*)(Wt + ((size_t)(kk * 8 + g) * 64 + lane) * 8);
  }

  f4vec acc[4][4];
#pragma unroll
  for (int i = 0; i < 4; ++i)
#pragma unroll
    for (int j = 0; j < 4; ++j) acc[i][j] = (f4vec){0.f, 0.f, 0.f, 0.f};

#pragma unroll
  for (int h = 0; h < 2; ++h)
#pragma unroll
    for (int kk = 0; kk < 2; ++kk) {
      s8vec a[4];
#pragma unroll
      for (int mi = 0; mi < 4; ++mi)
        a[mi] = *(const s8vec*)&Hs[h][kk][wvh * 4 + mi][lane][0];
#pragma unroll
      for (int mi = 0; mi < 4; ++mi)
#pragma unroll
        for (int ni = 0; ni < 4; ++ni)
          acc[mi][ni] = __builtin_amdgcn_mfma_f32_16x16x32_bf16(
              a[mi], bf[ni][kk], acc[mi][ni], 0, 0, 0);
    }

  // epilogue: D col = lane&15 (j within 16), row = (lane>>4)*4 + reg (v)
  const int lr = lane & 15;
  const int rh = lane >> 4;
#pragma unroll
  for (int mi = 0; mi < 4; ++mi) {
    const int vbase = v0 + wvh * 64 + mi * 16 + rh * 4;
#pragma unroll
    for (int np = 0; np < 2; ++np) {
      const int j  = wc * 32 + np * 16 + lr;
      const float bl = bias[j];
      const float bh = bias[j + 64];
      float vals[4];
#pragma unroll
      for (int r = 0; r < 4; ++r) {
        float lo = acc[mi][np][r] + bl;
        float hi = acc[mi][np + 2][r] + bh;
        float gv = lo / (1.0f + __expf(-hi));
        vals[r] = ((vbase + r) < NV) ? gv : 0.0f;
      }
#pragma unroll
      for (int r = 0; r < 4; ++r) {
        int vg = vbase + r;
        if (vg >= NMID && vg < 2 * NMID) {
          size_t oi = (size_t)(vg - NMID) * NBC + b * 64 + j;
          if (LAYER0) out[oi] = vals[r];
          else        out[oi] = fmaxf(out[oi], vals[r]);
        }
      }
      if (WRITEX) {   // tiled write: k = vbase..+3, n = b*64 + j
        int n   = b * 64 + j;
        int nt  = n >> 7, g2 = (n >> 4) & 7, ln2 = n & 15;
        int kk2 = vbase >> 5, hi2 = (vbase >> 3) & 3, jj0 = vbase & 7;
        ushort4 o;
        o.x = f2b(vals[0]); o.y = f2b(vals[1]);
        o.z = f2b(vals[2]); o.w = f2b(vals[3]);
        size_t dst = ((size_t)(nt * 96 + kk2) * 8 + g2) * 512 +
                     (size_t)(hi2 * 16 + ln2) * 8 + jj0;
        *(ushort4*)(xt + dst) = o;
      }
    }
  }
}

// ---------------------------------------------------------------------------
// Buffer rotation (no extra workspace): xa always holds the current tiled x
// (layerB writes x_next back into xa after the gemm has fully consumed it);
// Hbuf (25.2 MB) holds the two K-slice partials of the current layer.
extern "C" void kernel_launch(void* const* d_in, const int* in_sizes, int n_in,
                              void* d_out, int out_size, void* d_ws, size_t ws_size,
                              hipStream_t stream) {
  const float* x   = (const float*)d_in[0];
  const float* adj = (const float*)d_in[1];
  const float* W0  = (const float*)d_in[2];
  const float* b0  = (const float*)d_in[3];
  const float* W1  = (const float*)d_in[4];
  const float* b1  = (const float*)d_in[5];
  const float* W2  = (const float*)d_in[6];
  const float* b2  = (const float*)d_in[7];
  float* out = (float*)d_out;

  char* ws = (char*)d_ws;
  u16* adjt = (u16*)ws;                                  // 18,874,368 B
  u16* xa   = (u16*)(ws + 18874368);                     // 12,582,912 B
  u16* Hbuf = (u16*)(ws + 18874368 + 12582912);          // 25,165,824 B
  u16* Wt   = (u16*)(ws + 18874368 + 12582912 + 25165824); //   49,152 B
  // total ws use: ~56.7 MB

  const size_t FS = (size_t)3072 * NBC;   // full-M slot (layers 0/1)
  const size_t PS = (size_t)1152 * NBC;   // 9-tile slot (layer 2)
  const size_t R0 = (size_t)896 * NBC;    // layer-2 row-compaction offset

  // fused input conversion: adj (2304 blocks) | x (1536) | W (96)
  k_conv<<<3936, 256, 0, stream>>>(adj, x, W0, W1, W2, adjt, xa, Wt);

  // layer 0: full M, K split 2 -> 24*16*2 = 768 blocks = 3/CU
  k_gemm<48><<<768, 256, 0, stream>>>(adjt, xa, Hbuf, FS, 0, 24, 0, 96);
  k_layerB<1, 1><<<dim3(24, 32), 256, 0, stream>>>(
      Hbuf, Hbuf + FS, Wt, b0, xa, out, 0);
  // layer 1: full M
  k_gemm<48><<<768, 256, 0, stream>>>(adjt, xa, Hbuf, FS, 0, 24, 0, 96);
  k_layerB<0, 1><<<dim3(24, 32), 256, 0, stream>>>(
      Hbuf, Hbuf + FS, Wt + 8192, b1, xa, out, 0);
  // layer 2: rows [896,2048) (9 m-tiles), K split 2, rows stored compacted
  k_gemm<48><<<288, 256, 0, stream>>>(adjt, xa, Hbuf, PS, 7, 9, 896, 36);
  k_layerB<0, 0><<<dim3(9, 32), 256, 0, stream>>>(
      Hbuf - R0, Hbuf + PS - R0, Wt + 16384, b2, xa, out, 7);
}